// Round 6
// baseline (498.220 us; speedup 1.0000x reference)
//
#include <hip/hip_runtime.h>

#define EPS 1e-5f

typedef __attribute__((ext_vector_type(8))) short short8;
typedef __attribute__((ext_vector_type(4))) float f32x4;

// ---- ws layout ----
// shorts [0, 131072)      : shW frags, idx = (kq*256 + n)*8 + j, k = kq*8+j (BN0 scale folded)
// shorts [131072, 180224) : stW frags, idx = 131072 + s*16384 + (kq*128 + n')*8 + j,
//                           actual col n = n' (<64) or n'+64
#define C1_OFF   90112
#define C2_OFF   90368
#define STC1_OFF 90624
#define STC2_OFF 91392

// raw waitcnt immediates (gfx9 encoding): vmcnt[3:0], exp[6:4], lgkm[11:8], vmcnt_hi[15:14]
#define WAIT_VM(N)  __builtin_amdgcn_s_waitcnt(0x0F70 | (N))   // wait vmcnt<=N only
#define WAIT_LGKM0  __builtin_amdgcn_s_waitcnt(0xC07F)         // wait lgkmcnt(0) only
#define BARRIER()  do { __asm__ volatile("" ::: "memory"); __builtin_amdgcn_s_barrier(); \
                        __asm__ volatile("" ::: "memory"); } while (0)

__device__ inline unsigned short f2bf(float f) {
  unsigned u = __builtin_bit_cast(unsigned, f);
  u += 0x7FFFu + ((u >> 16) & 1u);
  return (unsigned short)(u >> 16);
}

__device__ inline short8 cvt8(f32x4 a, f32x4 b) {
  short8 r;
  r[0] = (short)f2bf(a[0]); r[1] = (short)f2bf(a[1]);
  r[2] = (short)f2bf(a[2]); r[3] = (short)f2bf(a[3]);
  r[4] = (short)f2bf(b[0]); r[5] = (short)f2bf(b[1]);
  r[6] = (short)f2bf(b[2]); r[7] = (short)f2bf(b[3]);
  return r;
}

__device__ inline void dma16(const void* g, void* l) {
  __builtin_amdgcn_global_load_lds(
      (__attribute__((address_space(1))) void*)(g),
      (__attribute__((address_space(3))) void*)(l), 16, 0, 0);
}

// ---------------- prep kernels (unchanged) ----------------
__global__ void prep_w(const float* __restrict__ shW, const float* __restrict__ stW,
                       const float* __restrict__ bn0_g, const float* __restrict__ bn0_v,
                       unsigned short* __restrict__ ws) {
  int t = blockIdx.x * 256 + threadIdx.x;
  if (t < 16384) {
    int kq = t >> 8, n = t & 255;
    short8 o;
#pragma unroll
    for (int j = 0; j < 8; ++j) {
      int k = kq * 8 + j;
      float scale = bn0_g[k] * rsqrtf(bn0_v[k] + EPS);
      o[j] = (short)f2bf(shW[k * 256 + n] * scale);
    }
    *(short8*)&ws[t * 8] = o;
  } else if (t < 16384 + 6144) {
    int r = t - 16384;
    int s = r >> 11, rem = r & 2047;
    int kq = rem >> 7, np = rem & 127;
    int n = np < 64 ? np : np + 64;
    short8 o;
#pragma unroll
    for (int j = 0; j < 8; ++j) o[j] = (short)f2bf(stW[(s * 128 + kq * 8 + j) * 256 + n]);
    *(short8*)&ws[131072 + r * 8] = o;
  }
}

__global__ void prep_b(const float* __restrict__ shW,
                       const float* __restrict__ bn0_g, const float* __restrict__ bn0_b,
                       const float* __restrict__ bn0_m, const float* __restrict__ bn0_v,
                       const float* __restrict__ sh_g, const float* __restrict__ sh_b,
                       const float* __restrict__ sh_m, const float* __restrict__ sh_v,
                       const float* __restrict__ st_g, const float* __restrict__ st_b,
                       const float* __restrict__ st_m, const float* __restrict__ st_v,
                       float* __restrict__ wsf) {
  const int n = blockIdx.x, t = threadIdx.x;
  float part = 0.f;
#pragma unroll
  for (int kk = 0; kk < 2; ++kk) {
    int k = t + kk * 256;
    float sc = bn0_g[k] * rsqrtf(bn0_v[k] + EPS);
    part += (bn0_b[k] - bn0_m[k] * sc) * shW[k * 256 + n];
  }
#pragma unroll
  for (int m = 1; m < 64; m <<= 1) part += __shfl_xor(part, m);
  __shared__ float wsum[4];
  if ((t & 63) == 0) wsum[t >> 6] = part;
  __syncthreads();
  if (t == 0) {
    float bias = wsum[0] + wsum[1] + wsum[2] + wsum[3];
    float c1 = sh_g[n] * rsqrtf(sh_v[n] + EPS);
    wsf[C1_OFF + n] = c1;
    wsf[C2_OFF + n] = (bias - sh_m[n]) * c1 + sh_b[n];
#pragma unroll
    for (int s = 0; s < 3; ++s) {
      float a = st_g[s * 256 + n] * rsqrtf(st_v[s * 256 + n] + EPS);
      wsf[STC1_OFF + s * 256 + n] = a;
      wsf[STC2_OFF + s * 256 + n] = st_b[s * 256 + n] - st_m[s * 256 + n] * a;
    }
  }
}

// ---------------- main fused streaming kernel ----------------
// 1024 blocks x 256 threads; block owns 128 rows = 4 tiles x 32 rows.
// All K-loop global reads (x AND weights) stream via global_load_lds into a
// 3-deep 20KB chunk ring (1 chunk = one K-step: 4KB x fp32 + 16KB B frags),
// paced by raw s_barrier + manual vmcnt(10) -> 2 chunks (40KB/block) always
// in flight. x global addresses are XOR-swizzled so LDS A-reads are 2-way
// bank-free despite the DMA's forced-contiguous destination.
__global__ __launch_bounds__(256) void tabnet_main(
    const float* __restrict__ x, const unsigned short* __restrict__ wsu,
    const float* __restrict__ wsf, const float* __restrict__ fW,
    const float* __restrict__ fb, float* __restrict__ out) {

  // ring: 3 x 20480 B  | sh frags: 8192 B | red: 1024 B
  __shared__ __align__(16) char slab[3 * 20480 + 8192 + 1024];
  unsigned short* sh = (unsigned short*)(slab + 61440);
  float* red = (float*)(slab + 69632);

  const int tid = threadIdx.x;
  const int wave = tid >> 6, lane = tid & 63;
  const int q = lane >> 4, l15 = lane & 15, l7 = l15 & 7;
  const int xsw = (lane & 7) ^ (lane >> 3);  // global-side swizzle for x DMA
  const long row0 = (long)blockIdx.x * 128;

  // issue one chunk g (tile g>>4, k-step g&15) into ring buffer bs
  auto issue_chunk = [&](int gi, int bs) {
    char* bufc = slab + bs * 20480;
    const int t = gi >> 4, st = gi & 15;
    const float* xsrc =
        x + (row0 + t * 32 + wave * 8 + (lane >> 3)) * 512 + st * 32 + xsw * 4;
    dma16(xsrc, bufc + wave * 1024);
    const unsigned short* bsrc = wsu + st * 8192 + wave * 2048 + lane * 8;
    char* bdst = bufc + 4096 + wave * 4096;
    dma16(bsrc, bdst);
    dma16(bsrc + 512, bdst + 1024);
    dma16(bsrc + 1024, bdst + 2048);
    dma16(bsrc + 1536, bdst + 3072);
  };

  issue_chunk(0, 0);
  issue_chunk(1, 1);
  issue_chunk(2, 2);

  f32x4 acc[2][4];
#pragma unroll
  for (int a = 0; a < 2; ++a)
#pragma unroll
    for (int b = 0; b < 4; ++b) acc[a][b] = (f32x4)0.f;

  int bsel = 0, isel = 0;  // ring index of current chunk / next issue

  for (int t = 0; t < 4; ++t) {
    for (int st = 0; st < 16; ++st) {
      const int g = t * 16 + st;
      // data-ready: chunk g complete when <= (issues younger than it) remain
      if (g < 62) WAIT_VM(10);
      else if (g == 62) WAIT_VM(5);
      else WAIT_VM(0);
      BARRIER();

      const float* xb = (const float*)(slab + bsel * 20480);
      const unsigned short* bb = (const unsigned short*)(slab + bsel * 20480 + 4096);
      short8 af[2];
#pragma unroll
      for (int mt = 0; mt < 2; ++mt) {
        const int row = mt * 16 + l15;
        f32x4 lo = *(const f32x4*)&xb[row * 32 + (((q * 2) ^ l7) << 2)];
        f32x4 hi = *(const f32x4*)&xb[row * 32 + (((q * 2 + 1) ^ l7) << 2)];
        af[mt] = cvt8(lo, hi);
      }
      short8 bf[4];
#pragma unroll
      for (int nt = 0; nt < 4; ++nt) {
        const int n = wave * 32 + (nt & 1) * 16 + ((nt >> 1) << 7) + l15;
        bf[nt] = *(const short8*)&bb[(q * 256 + n) * 8];
      }
#pragma unroll
      for (int nt = 0; nt < 4; ++nt)
#pragma unroll
        for (int mt = 0; mt < 2; ++mt)
          acc[mt][nt] =
              __builtin_amdgcn_mfma_f32_16x16x32_bf16(af[mt], bf[nt], acc[mt][nt], 0, 0, 0);

      WAIT_LGKM0;
      BARRIER();  // ring buffer bsel free
      if (g + 3 < 64) issue_chunk(g + 3, isel);
      if (++bsel == 3) bsel = 0;
      if (++isel == 3) isel = 0;
    }

    // ---- tile epilogue: BN + GLU in registers -> sh (A-frag layout, 32 rows) ----
#pragma unroll
    for (int nt = 0; nt < 2; ++nt) {
      const int c = wave * 32 + nt * 16 + l15;  // sh col in [0,128)
      const float v1 = wsf[C1_OFF + c], v2 = wsf[C2_OFF + c];
      const float g1 = wsf[C1_OFF + c + 128], g2 = wsf[C2_OFF + c + 128];
#pragma unroll
      for (int mt = 0; mt < 2; ++mt)
#pragma unroll
        for (int r = 0; r < 4; ++r) {
          float y1 = acc[mt][nt][r] * v1 + v2;
          float y2 = acc[mt][nt + 2][r] * g1 + g2;
          float sg = __builtin_amdgcn_rcpf(1.f + __expf(-y2));
          int row = mt * 16 + 4 * q + r;
          sh[((c >> 3) * 32 + row) * 8 + (c & 7)] = f2bf(y1 * sg);
        }
    }
#pragma unroll
    for (int a = 0; a < 2; ++a)
#pragma unroll
      for (int b = 0; b < 4; ++b) acc[a][b] = (f32x4)0.f;
    WAIT_LGKM0;
    BARRIER();

    // ---- phase 2: 3 steps, K=128; A from sh, B register-loaded (L2-hot) ----
    float agg[2][4];
#pragma unroll
    for (int a = 0; a < 2; ++a)
#pragma unroll
      for (int r = 0; r < 4; ++r) agg[a][r] = 0.f;

    const int n1 = wave * 16 + l15;  // value col in [0,64); gate n' = n1+64
    short8 bsv, bsg;
    {
      const unsigned short* wb = wsu + 131072;
      bsv = *(const short8*)&wb[(q * 128 + n1) * 8];
      bsg = *(const short8*)&wb[(q * 128 + 64 + n1) * 8];
    }
    for (int s = 0; s < 3; ++s) {
      f32x4 acc2[2][2];
#pragma unroll
      for (int a = 0; a < 2; ++a) { acc2[a][0] = (f32x4)0.f; acc2[a][1] = (f32x4)0.f; }
#pragma unroll
      for (int ks = 0; ks < 4; ++ks) {
        short8 cv = bsv, cg = bsg;
        if (!(s == 2 && ks == 3)) {
          int s2 = ks < 3 ? s : s + 1, ks2 = ks < 3 ? ks + 1 : 0;
          const unsigned short* wb = wsu + 131072 + s2 * 16384;
          bsv = *(const short8*)&wb[((ks2 * 4 + q) * 128 + n1) * 8];
          bsg = *(const short8*)&wb[((ks2 * 4 + q) * 128 + 64 + n1) * 8];
        }
        const int kq = ks * 4 + q;
        short8 af2[2];
#pragma unroll
        for (int mt = 0; mt < 2; ++mt)
          af2[mt] = *(const short8*)&sh[(kq * 32 + mt * 16 + l15) * 8];
#pragma unroll
        for (int mt = 0; mt < 2; ++mt) {
          acc2[mt][0] = __builtin_amdgcn_mfma_f32_16x16x32_bf16(af2[mt], cv, acc2[mt][0], 0, 0, 0);
          acc2[mt][1] = __builtin_amdgcn_mfma_f32_16x16x32_bf16(af2[mt], cg, acc2[mt][1], 0, 0, 0);
        }
      }
      const float a1 = wsf[STC1_OFF + s * 256 + n1], b1 = wsf[STC2_OFF + s * 256 + n1];
      const float a2 = wsf[STC1_OFF + s * 256 + n1 + 128], b2 = wsf[STC2_OFF + s * 256 + n1 + 128];
#pragma unroll
      for (int mt = 0; mt < 2; ++mt)
#pragma unroll
        for (int r = 0; r < 4; ++r) {
          float y1 = acc2[mt][0][r] * a1 + b1;
          float y2 = acc2[mt][1][r] * a2 + b2;
          agg[mt][r] += y1 * __builtin_amdgcn_rcpf(1.f + __expf(-y2));
        }
    }

    // ---- final per tile: out = agg @ fW + fb ----
    {
      const float w0 = fW[n1 * 2], w1 = fW[n1 * 2 + 1];
#pragma unroll
      for (int mt = 0; mt < 2; ++mt)
#pragma unroll
        for (int r = 0; r < 4; ++r) {
          float p0 = agg[mt][r] * w0;
          float p1 = agg[mt][r] * w1;
#pragma unroll
          for (int m = 1; m < 16; m <<= 1) {
            p0 += __shfl_xor(p0, m);
            p1 += __shfl_xor(p1, m);
          }
          if (l15 == 0) {
            int row = mt * 16 + 4 * q + r;
            red[(row * 2 + 0) * 4 + wave] = p0;
            red[(row * 2 + 1) * 4 + wave] = p1;
          }
        }
    }
    WAIT_LGKM0;
    BARRIER();
    if (tid < 64) {
      int row = tid >> 1, o = tid & 1;
      float v = fb[o];
#pragma unroll
      for (int w = 0; w < 4; ++w) v += red[(row * 2 + o) * 4 + w];
      out[(row0 + t * 32 + row) * 2 + o] = v;
    }
    BARRIER();  // protect sh/red before next tile reuses them
  }
}

extern "C" void kernel_launch(void* const* d_in, const int* in_sizes, int n_in,
                              void* d_out, int out_size, void* d_ws, size_t ws_size,
                              hipStream_t stream) {
  const float* x     = (const float*)d_in[0];
  const float* bn0_g = (const float*)d_in[1];
  const float* bn0_b = (const float*)d_in[2];
  const float* bn0_m = (const float*)d_in[3];
  const float* bn0_v = (const float*)d_in[4];
  const float* shW   = (const float*)d_in[5];
  const float* sh_g  = (const float*)d_in[6];
  const float* sh_b  = (const float*)d_in[7];
  const float* sh_m  = (const float*)d_in[8];
  const float* sh_v  = (const float*)d_in[9];
  const float* stW   = (const float*)d_in[10];
  const float* st_g  = (const float*)d_in[11];
  const float* st_b  = (const float*)d_in[12];
  const float* st_m  = (const float*)d_in[13];
  const float* st_v  = (const float*)d_in[14];
  // d_in[15..19] = atW, at_g, at_b, at_m, at_v : dead code (never feeds output)
  const float* fW    = (const float*)d_in[20];
  const float* fb    = (const float*)d_in[21];

  unsigned short* wsu = (unsigned short*)d_ws;
  float* wsf = (float*)d_ws;

  prep_w<<<88, 256, 0, stream>>>(shW, stW, bn0_g, bn0_v, wsu);
  prep_b<<<256, 256, 0, stream>>>(shW, bn0_g, bn0_b, bn0_m, bn0_v, sh_g, sh_b, sh_m,
                                  sh_v, st_g, st_b, st_m, st_v, wsf);
  tabnet_main<<<1024, 256, 0, stream>>>(x, wsu, wsf, fW, fb, (float*)d_out);
}